// Round 1
// baseline (449.760 us; speedup 1.0000x reference)
//
#include <hip/hip_runtime.h>

#define D 128
#define EPSV 1e-5f

typedef __attribute__((ext_vector_type(8))) short bf16x8;
typedef __attribute__((ext_vector_type(4))) float f32x4;

__device__ __forceinline__ short f2bf(float f){
  unsigned u = __float_as_uint(f);
  u += 0x7fffu + ((u >> 16) & 1u);          // RNE
  return (short)(u >> 16);
}
__device__ __forceinline__ float bflo(unsigned u){ return __uint_as_float(u << 16); }
__device__ __forceinline__ float bfhi(unsigned u){ return __uint_as_float(u & 0xffff0000u); }
__device__ __forceinline__ float bf2f(short s){ return __uint_as_float(((unsigned)(unsigned short)s) << 16); }
__device__ __forceinline__ unsigned packbf(float a, float b){
  unsigned lo = (unsigned short)f2bf(a);
  unsigned hi = (unsigned short)f2bf(b);
  return lo | (hi << 16);
}

// Coherent (agent-scope) loads/stores: bypass non-coherent per-XCD caches so
// intra-kernel cross-phase data (count->scan->scatter) is visible across XCDs.
__device__ __forceinline__ int   ld_coh_i(const int* p){ return __hip_atomic_load(p, __ATOMIC_RELAXED, __HIP_MEMORY_SCOPE_AGENT); }
__device__ __forceinline__ float ld_coh_f(const float* p){ return __hip_atomic_load(p, __ATOMIC_RELAXED, __HIP_MEMORY_SCOPE_AGENT); }
__device__ __forceinline__ void  st_coh_i(int* p, int v){ __hip_atomic_store(p, v, __ATOMIC_RELAXED, __HIP_MEMORY_SCOPE_AGENT); }
__device__ __forceinline__ void  st_coh_f(float* p, float v){ __hip_atomic_store(p, v, __ATOMIC_RELAXED, __HIP_MEMORY_SCOPE_AGENT); }

// Fused init: detect int64-vs-int32 edge layout (block 0), zero deg/fill/gpart/
// scan-flags/phase-counters, transpose W1,W2 -> bf16 [out_col][k].
__global__ void k_init(int N, int E, const int* __restrict__ ei, int* __restrict__ flag,
                       int* __restrict__ deg, int* __restrict__ fill, float* __restrict__ gpart,
                       int* __restrict__ sflg, int* __restrict__ pd,
                       const float* __restrict__ W1, const float* __restrict__ W2,
                       short* __restrict__ w1t, short* __restrict__ w2t){
  int i = blockIdx.x*blockDim.x + threadIdx.x;
  if (i < N){ deg[i] = 0; fill[i] = 0; }
  if (i < D*D){
    int j = i >> 7, k = i & 127;
    w1t[i] = f2bf(W1[k*D + j]);
    w2t[i] = f2bf(W2[k*D + j]);
  }
  if (i < 2048) gpart[i] = 0.f;
  if (i < 128) sflg[i] = 0;
  if (i < 2) pd[i] = 0;
  if (blockIdx.x == 0){
    __shared__ int any;
    int t = threadIdx.x;
    if (t == 0) any = 0;
    __syncthreads();
    if (2*t+1 < 2*E && ei[2*t+1] != 0) atomicOr(&any, 1);
    __syncthreads();
    if (t == 0) flag[0] = (any == 0) ? 1 : 0;   // 1 => int64 layout
  }
}

// GEMM v6: B (128x128 bf16 = 32KB) in LDS, XOR-swizzled; MFMA operands swapped;
// epilogue bounces through per-wave swizzled LDS tile for coalesced stores.
// MODE 1 = f32 A (cast), with the FULL edge preprocessing appended to the grid
// as phase-ordered block ranges: [count edges] -> [decoupled-lookback scan]
// -> [CSR scatter]. Phases sequence via device-scope counters pd[0]/pd[1];
// every wait points only at lower block IDs (in-order dispatch => no deadlock).
// Cross-phase data uses agent-scope coherent loads/stores (per-XCD L2s are not
// coherent within a dispatch). MODE 2 = bf16 A with fused BatchNorm+ReLU.
template<int MODE>
__global__ __launch_bounds__(256, 2) void k_gemm(const void* __restrict__ A,
                                const short* __restrict__ BT, short* __restrict__ C, int N,
                                const float* __restrict__ gpart, const float* __restrict__ gamma,
                                const float* __restrict__ beta,
                                const int* __restrict__ ei, int E, const int* __restrict__ flag,
                                int* __restrict__ deg, int ngemmb,
                                int* __restrict__ rowp, float* __restrict__ dinvP,
                                int* __restrict__ fillP, int2* __restrict__ epack,
                                int* __restrict__ s_agg, int* __restrict__ s_inc,
                                int* __restrict__ s_flg, int* __restrict__ pd,
                                int cntb, int scanb){
  __shared__ short ldsB[16384];     // [row=col-of-W 128][k 128], chunk-swizzled
  __shared__ short ldsC[4*2048];    // per-wave 16x128 epilogue tile
  __shared__ __align__(16) float s_sc[128];
  __shared__ __align__(16) float s_sh[128];

  if (MODE == 1 && (int)blockIdx.x >= ngemmb){
    int cb = blockIdx.x - ngemmb;
    int t = threadIdx.x;
    if (cb < cntb){
      // ---- phase 1: degree count ----
      int e0 = cb*1024 + t;
      int f = flag[0];
      #pragma unroll
      for (int r = 0; r < 4; ++r){
        int e = e0 + r*256;
        if (e < E){
          int d = f ? ei[2*E + 2*e] : ei[E + e];
          atomicAdd(&deg[d], 1);
        }
      }
      __syncthreads();                      // drains all threads' atomics (vmcnt)
      if (t == 0){ __threadfence(); atomicAdd(&pd[0], 1); }
      return;
    }
    if (cb < cntb + scanb){
      // ---- phase 2: exclusive scan of deg -> rowp, plus dinv ----
      int sb = cb - cntb;
      int* sh = (int*)ldsB;                 // reuse gemm LDS as scan scratch
      if (t == 0){
        while (__hip_atomic_load(&pd[0], __ATOMIC_ACQUIRE, __HIP_MEMORY_SCOPE_AGENT) < cntb)
          __builtin_amdgcn_s_sleep(8);
      }
      __syncthreads();
      int base = sb*1024 + t*4;
      int c0 = (base+0 < N) ? ld_coh_i(&deg[base+0]) : 0;
      int c1 = (base+1 < N) ? ld_coh_i(&deg[base+1]) : 0;
      int c2 = (base+2 < N) ? ld_coh_i(&deg[base+2]) : 0;
      int c3 = (base+3 < N) ? ld_coh_i(&deg[base+3]) : 0;
      int s = c0 + c1 + c2 + c3;
      sh[t] = s; __syncthreads();
      for (int d = 1; d < 256; d <<= 1){
        int v = (t >= d) ? sh[t-d] : 0;
        __syncthreads();
        sh[t] += v;
        __syncthreads();
      }
      int total = sh[255];
      if (t == 0){
        atomicExch(&s_agg[sb], total);
        __threadfence();
        atomicExch(&s_flg[sb], 1);
        int ex = 0;
        for (int i = sb-1; i >= 0; ){
          int f;
          while ((f = atomicAdd(&s_flg[i], 0)) == 0) __builtin_amdgcn_s_sleep(1);
          if (f == 2){ ex += atomicAdd(&s_inc[i], 0); break; }
          ex += atomicAdd(&s_agg[i], 0); --i;
        }
        atomicExch(&s_inc[sb], ex + total);
        __threadfence();
        atomicExch(&s_flg[sb], 2);
        sh[256] = ex;
      }
      __syncthreads();
      int ex = sh[256];
      int o = sh[t] - s + ex;
      if (base+0 < N){ st_coh_i(&rowp[base+0], o); st_coh_f(&dinvP[base+0], rsqrtf((float)(c0+1))); } o += c0;
      if (base+1 < N){ st_coh_i(&rowp[base+1], o); st_coh_f(&dinvP[base+1], rsqrtf((float)(c1+1))); } o += c1;
      if (base+2 < N){ st_coh_i(&rowp[base+2], o); st_coh_f(&dinvP[base+2], rsqrtf((float)(c2+1))); } o += c2;
      if (base+3 < N){ st_coh_i(&rowp[base+3], o); st_coh_f(&dinvP[base+3], rsqrtf((float)(c3+1))); }
      __syncthreads();                      // drain coherent stores
      if (t == 0){ __threadfence(); atomicAdd(&pd[1], 1); }
      return;
    }
    // ---- phase 3: CSR scatter (edge -> epack at rowp[d]+fill[d]++) ----
    {
      int eb = cb - cntb - scanb;
      if (t == 0){
        while (__hip_atomic_load(&pd[1], __ATOMIC_ACQUIRE, __HIP_MEMORY_SCOPE_AGENT) < scanb)
          __builtin_amdgcn_s_sleep(8);
      }
      __syncthreads();
      int f = flag[0];
      int e0 = eb*1024 + t;
      #pragma unroll
      for (int r = 0; r < 4; ++r){
        int e = e0 + r*256;
        if (e < E){
          int sE, dE;
          if (f){ sE = ei[2*e]; dE = ei[2*E + 2*e]; }
          else  { sE = ei[e];   dE = ei[E + e];     }
          int pos = ld_coh_i(&rowp[dE]) + atomicAdd(&fillP[dE], 1);
          int2 ev; ev.x = sE;
          ev.y = __float_as_int(ld_coh_f(&dinvP[sE]) * ld_coh_f(&dinvP[dE]));
          epack[pos] = ev;
        }
      }
      return;
    }
  }

  int w = threadIdx.x >> 6;
  int lane = threadIdx.x & 63;
  int m = lane & 15, quad = lane >> 4;

  if (MODE == 2 && threadIdx.x < 128){
    int f = threadIdx.x;
    float s = 0.f, q = 0.f;
    #pragma unroll
    for (int i = 0; i < 8; ++i){ s += gpart[i*256 + f]; q += gpart[i*256 + 128 + f]; }
    float inv = 1.f / (float)N;
    float mean = s * inv;
    float var  = q * inv - mean*mean;   // biased, matches torch BN batch stats
    float sc = gamma[f] * rsqrtf(var + EPSV);
    s_sc[f] = sc;
    s_sh[f] = beta[f] - mean * sc;
  }
  // stage B into LDS with chunk XOR swizzle
  {
    const bf16x8* BTv = (const bf16x8*)BT;
    bf16x8* Bw = (bf16x8*)ldsB;
    for (int g = threadIdx.x; g < 2048; g += 256){
      int row = g >> 4, ch = g & 15;
      Bw[row*16 + (ch ^ (row & 15))] = BTv[g];
    }
  }
  __syncthreads();
  const bf16x8* Bv = (const bf16x8*)ldsB;
  short* cw = ldsC + w*2048;

  int tiles = (N + 31) >> 5;
  int wid = blockIdx.x*4 + w;
  int wstride = ngemmb*4;
  for (int tile = wid; tile < tiles; tile += wstride){
    int r0 = tile << 5;
    bf16x8 a[2][4];
    #pragma unroll
    for (int g = 0; g < 2; ++g){
      int row = r0 + g*16 + m;
      if (row >= N) row = N - 1;
      #pragma unroll
      for (int kc = 0; kc < 4; ++kc){
        int k0 = kc*32 + quad*8;
        if (MODE == 1){
          const float* Af = (const float*)A + (size_t)row*D + k0;
          float4 u = *(const float4*)Af;
          float4 v = *(const float4*)(Af + 4);
          bf16x8 tv;
          tv[0]=f2bf(u.x); tv[1]=f2bf(u.y); tv[2]=f2bf(u.z); tv[3]=f2bf(u.w);
          tv[4]=f2bf(v.x); tv[5]=f2bf(v.y); tv[6]=f2bf(v.z); tv[7]=f2bf(v.w);
          a[g][kc] = tv;
        } else {
          bf16x8 raw = *(const bf16x8*)((const short*)A + (size_t)row*D + k0);
          float4 s0v = *(const float4*)(s_sc + k0);
          float4 s1v = *(const float4*)(s_sc + k0 + 4);
          float4 h0v = *(const float4*)(s_sh + k0);
          float4 h1v = *(const float4*)(s_sh + k0 + 4);
          bf16x8 tv;
          tv[0] = f2bf(fmaxf(fmaf(bf2f(raw[0]), s0v.x, h0v.x), 0.f));
          tv[1] = f2bf(fmaxf(fmaf(bf2f(raw[1]), s0v.y, h0v.y), 0.f));
          tv[2] = f2bf(fmaxf(fmaf(bf2f(raw[2]), s0v.z, h0v.z), 0.f));
          tv[3] = f2bf(fmaxf(fmaf(bf2f(raw[3]), s0v.w, h0v.w), 0.f));
          tv[4] = f2bf(fmaxf(fmaf(bf2f(raw[4]), s1v.x, h1v.x), 0.f));
          tv[5] = f2bf(fmaxf(fmaf(bf2f(raw[5]), s1v.y, h1v.y), 0.f));
          tv[6] = f2bf(fmaxf(fmaf(bf2f(raw[6]), s1v.z, h1v.z), 0.f));
          tv[7] = f2bf(fmaxf(fmaf(bf2f(raw[7]), s1v.w, h1v.w), 0.f));
          a[g][kc] = tv;
        }
      }
    }
    f32x4 acc[2][8];
    #pragma unroll
    for (int g = 0; g < 2; ++g)
      #pragma unroll
      for (int c = 0; c < 8; ++c) acc[g][c] = (f32x4){0.f,0.f,0.f,0.f};
    #pragma unroll
    for (int kc = 0; kc < 4; ++kc){
      bf16x8 bb[8];
      #pragma unroll
      for (int c = 0; c < 8; ++c)
        bb[c] = Bv[(c*16 + m)*16 + ((kc*4 + quad) ^ m)];
      #pragma unroll
      for (int g = 0; g < 2; ++g)
        #pragma unroll
        for (int c = 0; c < 8; ++c)
          acc[g][c] = __builtin_amdgcn_mfma_f32_16x16x32_bf16(bb[c], a[g][kc], acc[g][c], 0, 0, 0);
    }
    // epilogue: per 16-row group, pack -> LDS (swizzled) -> coalesced dwordx4
    #pragma unroll
    for (int g = 0; g < 2; ++g){
      #pragma unroll
      for (int c = 0; c < 8; ++c){
        uint2 v;
        v.x = packbf(acc[g][c][0], acc[g][c][1]);
        v.y = packbf(acc[g][c][2], acc[g][c][3]);
        int x = c*2 + (quad >> 1);
        *(uint2*)&cw[m*128 + ((x ^ m) << 3) + ((quad & 1) << 2)] = v;
      }
      asm volatile("s_waitcnt lgkmcnt(0)" ::: "memory");
      #pragma unroll
      for (int rg = 0; rg < 4; ++rg){
        int lrow = rg*4 + quad;
        int rr = r0 + g*16 + lrow;
        uint4 v = *(const uint4*)&cw[lrow*128 + ((m ^ lrow) << 3)];
        if (rr < N) *(uint4*)(C + (size_t)rr*D + m*8) = v;
      }
      asm volatile("s_waitcnt lgkmcnt(0)" ::: "memory");
    }
  }
}

// Aggregation v3 (software-pipelined): grid-stride, one node per wave per step;
// lane p holds features 2p,2p+1. Prefetch next node's (rowp,deg,dinv,self-row,
// epack chunk) while current node's gathers are in flight. Gathers issue in
// batches of 8 independent loads via shfl broadcast. OUTF32==0 adds BN stats.
template<int OUTF32>
__global__ __launch_bounds__(256) void k_agg(const short* __restrict__ H, const int* __restrict__ rowp,
        const int* __restrict__ deg, const int2* __restrict__ epack, const float* __restrict__ dinv,
        const float* __restrict__ bias, void* __restrict__ out, int N, float* __restrict__ gpart){
  int w = threadIdx.x >> 6, p = threadIdx.x & 63;
  int wid = blockIdx.x*4 + w, wstride = gridDim.x*4;
  const unsigned* Hu = (const unsigned*)H;
  float S0=0.f, S1=0.f, Q0=0.f, Q1=0.f;
  float bb0=0.f, bb1=0.f;
  if (OUTF32){ bb0 = bias[2*p]; bb1 = bias[2*p+1]; }

  int n = wid;
  int start=0, cnt=0; float d1=0.f; unsigned u=0; int2 ev; ev.x=0; ev.y=0;
  if (n < N){
    start = rowp[n]; cnt = deg[n]; d1 = dinv[n];
    u = Hu[(size_t)n*64 + p];
    int nb = cnt < 64 ? cnt : 64;
    if (p < nb) ev = epack[start + p];
  }
  while (n < N){
    int n2 = n + wstride;
    int start2=0, cnt2=0; float d12=0.f; unsigned u2=0; int2 ev2; ev2.x=0; ev2.y=0;
    if (n2 < N){
      start2 = rowp[n2]; cnt2 = deg[n2]; d12 = dinv[n2];
      u2 = Hu[(size_t)n2*64 + p];
      int nb2 = cnt2 < 64 ? cnt2 : 64;
      if (p < nb2) ev2 = epack[start2 + p];
    }
    float w0 = d1*d1;
    float a0 = w0 * bflo(u), a1 = w0 * bfhi(u);
    int nb = cnt < 64 ? cnt : 64;
    for (int j = 0; j < nb; j += 8){
      int s0 = __shfl(ev.x, j+0), s1 = __shfl(ev.x, j+1);
      int s2 = __shfl(ev.x, j+2), s3 = __shfl(ev.x, j+3);
      int s4 = __shfl(ev.x, j+4), s5 = __shfl(ev.x, j+5);
      int s6 = __shfl(ev.x, j+6), s7 = __shfl(ev.x, j+7);
      float f0 = __int_as_float(__shfl(ev.y, j+0));
      float f1 = __int_as_float(__shfl(ev.y, j+1));
      float f2 = __int_as_float(__shfl(ev.y, j+2));
      float f3 = __int_as_float(__shfl(ev.y, j+3));
      float f4 = __int_as_float(__shfl(ev.y, j+4));
      float f5 = __int_as_float(__shfl(ev.y, j+5));
      float f6 = __int_as_float(__shfl(ev.y, j+6));
      float f7 = __int_as_float(__shfl(ev.y, j+7));
      unsigned u0 = Hu[(size_t)s0*64 + p], u1 = Hu[(size_t)s1*64 + p];
      unsigned u2g = Hu[(size_t)s2*64 + p], u3 = Hu[(size_t)s3*64 + p];
      unsigned u4 = Hu[(size_t)s4*64 + p], u5 = Hu[(size_t)s5*64 + p];
      unsigned u6 = Hu[(size_t)s6*64 + p], u7 = Hu[(size_t)s7*64 + p];
      a0 = fmaf(f0, bflo(u0), a0); a1 = fmaf(f0, bfhi(u0), a1);
      a0 = fmaf(f1, bflo(u1), a0); a1 = fmaf(f1, bfhi(u1), a1);
      a0 = fmaf(f2, bflo(u2g), a0); a1 = fmaf(f2, bfhi(u2g), a1);
      a0 = fmaf(f3, bflo(u3), a0); a1 = fmaf(f3, bfhi(u3), a1);
      a0 = fmaf(f4, bflo(u4), a0); a1 = fmaf(f4, bfhi(u4), a1);
      a0 = fmaf(f5, bflo(u5), a0); a1 = fmaf(f5, bfhi(u5), a1);
      a0 = fmaf(f6, bflo(u6), a0); a1 = fmaf(f6, bfhi(u6), a1);
      a0 = fmaf(f7, bflo(u7), a0); a1 = fmaf(f7, bfhi(u7), a1);
    }
    // rare overflow chunks (deg > 64)
    for (int base = 64; base < cnt; base += 64){
      int nbx = cnt - base; if (nbx > 64) nbx = 64;
      int2 evx; evx.x = 0; evx.y = 0;
      if (p < nbx) evx = epack[start + base + p];
      for (int j = 0; j < nbx; j += 8){
        #pragma unroll
        for (int q2 = 0; q2 < 8; ++q2){
          int sx = __shfl(evx.x, j+q2);
          float fx = __int_as_float(__shfl(evx.y, j+q2));
          unsigned ux = Hu[(size_t)sx*64 + p];
          a0 = fmaf(fx, bflo(ux), a0); a1 = fmaf(fx, bfhi(ux), a1);
        }
      }
    }
    if (OUTF32){
      float2 r; r.x = a0 + bb0; r.y = a1 + bb1;
      ((float2*)out)[(size_t)n*64 + p] = r;
    } else {
      ((unsigned*)out)[(size_t)n*64 + p] = packbf(a0, a1);
      S0 += a0; Q0 += a0*a0; S1 += a1; Q1 += a1*a1;
    }
    n = n2; start = start2; cnt = cnt2; d1 = d12; u = u2; ev = ev2;
  }
  if (!OUTF32){
    __shared__ float ls[1024];
    int base = w*256;
    ls[base + 2*p]       = S0;
    ls[base + 2*p + 1]   = S1;
    ls[base + 128 + 2*p]     = Q0;
    ls[base + 128 + 2*p + 1] = Q1;
    __syncthreads();
    int t = threadIdx.x;   // t<128: sum[f=t]; t>=128: sq[f=t-128]
    float v = ls[t] + ls[256 + t] + ls[512 + t] + ls[768 + t];
    atomicAdd(&gpart[(blockIdx.x & 7)*256 + t], v);
  }
}

extern "C" void kernel_launch(void* const* d_in, const int* in_sizes, int n_in,
                              void* d_out, int out_size, void* d_ws, size_t ws_size,
                              hipStream_t stream){
  const float* x   = (const float*)d_in[0];
  const int*   ei  = (const int*)  d_in[1];
  const float* W1  = (const float*)d_in[2];
  // d_in[3] = b1: cancels in BatchNorm, unused
  const float* g1  = (const float*)d_in[4];
  const float* be1 = (const float*)d_in[5];
  const float* W2  = (const float*)d_in[6];
  const float* b2  = (const float*)d_in[7];
  float* out = (float*)d_out;
  int N = in_sizes[0] / D;
  int E = in_sizes[1] / 2;

  char* w = (char*)d_ws;
  auto carve = [&](size_t bytes)->char*{ char* p = w; w += (bytes + 255) & ~(size_t)255; return p; };
  int*   flag  = (int*)  carve(256);
  int*   degA  = (int*)  carve((size_t)N*4);
  int*   fillA = (int*)  carve((size_t)N*4);
  float* dinvA = (float*)carve((size_t)N*4);
  int*   rowp  = (int*)  carve((size_t)N*4);
  int*   sagg  = (int*)  carve(512);
  int*   sinc  = (int*)  carve(512);
  int*   sflg  = (int*)  carve(512);
  int*   pd    = (int*)  carve(256);
  int2*  epack = (int2*) carve((size_t)E*8);
  float* gpart = (float*)carve(2048*4);
  short* w1t   = (short*)carve((size_t)D*D*2);
  short* w2t   = (short*)carve((size_t)D*D*2);
  short* h1    = (short*)carve((size_t)N*D*2);   // GEMM1 out; reused as GEMM2 out
  short* hb    = (short*)carve((size_t)N*D*2);   // agg1 out (pre-BN h)

  const int TB = 256;
  int NBt = (N + TB - 1) / TB;
  int SCANB = (N + 1023) / 1024;
  int GEMMB = 512;                 // gemm blocks (2-3/CU by LDS)
  int CNTB  = (E + 1023) / 1024;   // count blocks
  int SCATB = (E + 1023) / 1024;   // scatter blocks (4 edges/thread)
  int AGGB  = 2048;                // 8 blocks/CU = 32 waves/CU

  k_init    <<<NBt, TB, 0, stream>>>(N, E, ei, flag, degA, fillA, gpart, sflg, pd, W1, W2, w1t, w2t);
  // gemm1 + full edge preprocessing in one dispatch (count -> scan -> scatter
  // phase-sequenced behind the persistent gemm blocks)
  k_gemm<1> <<<GEMMB + CNTB + SCANB + SCATB, 256, 0, stream>>>(x, w1t, h1, N,
                nullptr, nullptr, nullptr,
                ei, E, flag, degA, GEMMB,
                rowp, dinvA, fillA, epack, sagg, sinc, sflg, pd, CNTB, SCANB);
  k_agg<0>  <<<AGGB, 256, 0, stream>>>(h1, rowp, degA, epack, dinvA, nullptr, hb, N, gpart);
  k_gemm<2> <<<GEMMB, 256, 0, stream>>>(hb, w2t, h1, N, gpart, g1, be1,
                nullptr, 0, nullptr, nullptr, GEMMB,
                nullptr, nullptr, nullptr, nullptr, nullptr, nullptr, nullptr, nullptr, 0, 0);
  k_agg<1>  <<<AGGB, 256, 0, stream>>>(h1, rowp, degA, epack, dinvA, b2, out, N, nullptr);
}

// Round 2
// 276.205 us; speedup vs baseline: 1.6284x; 1.6284x over previous
//
#include <hip/hip_runtime.h>

#define D 128
#define EPSV 1e-5f

typedef __attribute__((ext_vector_type(8))) short bf16x8;
typedef __attribute__((ext_vector_type(4))) float f32x4;

__device__ __forceinline__ short f2bf(float f){
  unsigned u = __float_as_uint(f);
  u += 0x7fffu + ((u >> 16) & 1u);          // RNE
  return (short)(u >> 16);
}
__device__ __forceinline__ float bflo(unsigned u){ return __uint_as_float(u << 16); }
__device__ __forceinline__ float bfhi(unsigned u){ return __uint_as_float(u & 0xffff0000u); }
__device__ __forceinline__ float bf2f(short s){ return __uint_as_float(((unsigned)(unsigned short)s) << 16); }
__device__ __forceinline__ unsigned packbf(float a, float b){
  unsigned lo = (unsigned short)f2bf(a);
  unsigned hi = (unsigned short)f2bf(b);
  return lo | (hi << 16);
}

// Fused init: detect int64-vs-int32 edge layout (block 0), zero deg/gpart/
// scan-flags, transpose W1,W2 -> bf16 [out_col][k] (16B-contiguous B frags).
__global__ void k_init(int N, int E, const int* __restrict__ ei, int* __restrict__ flag,
                       int* __restrict__ deg, float* __restrict__ gpart,
                       int* __restrict__ sflg,
                       const float* __restrict__ W1, const float* __restrict__ W2,
                       short* __restrict__ w1t, short* __restrict__ w2t){
  int i = blockIdx.x*blockDim.x + threadIdx.x;
  if (i < N) deg[i] = 0;
  if (i < D*D){
    int j = i >> 7, k = i & 127;
    w1t[i] = f2bf(W1[k*D + j]);
    w2t[i] = f2bf(W2[k*D + j]);
  }
  if (i < 2048) gpart[i] = 0.f;
  if (i < 128) sflg[i] = 0;
  if (blockIdx.x == 0){
    __shared__ int any;
    int t = threadIdx.x;
    if (t == 0) any = 0;
    __syncthreads();
    if (2*t+1 < 2*E && ei[2*t+1] != 0) atomicOr(&any, 1);
    __syncthreads();
    if (t == 0) flag[0] = (any == 0) ? 1 : 0;   // 1 => int64 layout
  }
}

// One-kernel scan: per-1024-node block sums + decoupled lookback (device-scope
// atomics; all 98 blocks co-resident => deadlock-free). Writes rowp, rowp2
// (scatter's atomic cursor) AND dinv.
__global__ void k_scan(const int* __restrict__ deg, int N, int* __restrict__ rowp,
                       int* __restrict__ rowp2,
                       float* __restrict__ dinv, int* __restrict__ s_agg,
                       int* __restrict__ s_inc, int* __restrict__ s_flg){
  __shared__ int sh[256];
  __shared__ int s_ex;
  int b = blockIdx.x, t = threadIdx.x;
  int base = b*1024 + t*4;
  int c0 = (base+0 < N) ? deg[base+0] : 0;
  int c1 = (base+1 < N) ? deg[base+1] : 0;
  int c2 = (base+2 < N) ? deg[base+2] : 0;
  int c3 = (base+3 < N) ? deg[base+3] : 0;
  int s = c0 + c1 + c2 + c3;
  sh[t] = s; __syncthreads();
  for (int d = 1; d < 256; d <<= 1){
    int v = (t >= d) ? sh[t-d] : 0;
    __syncthreads();
    sh[t] += v;
    __syncthreads();
  }
  int total = sh[255];
  if (t == 0){
    atomicExch(&s_agg[b], total);
    __threadfence();
    atomicExch(&s_flg[b], 1);
    int ex = 0;
    for (int i = b-1; i >= 0; ){
      int f;
      while ((f = atomicAdd(&s_flg[i], 0)) == 0) __builtin_amdgcn_s_sleep(1);
      if (f == 2){ ex += atomicAdd(&s_inc[i], 0); break; }
      ex += atomicAdd(&s_agg[i], 0); --i;
    }
    atomicExch(&s_inc[b], ex + total);
    __threadfence();
    atomicExch(&s_flg[b], 2);
    s_ex = ex;
  }
  __syncthreads();
  int o = sh[t] - s + s_ex;
  if (base+0 < N){ rowp[base+0] = o; rowp2[base+0] = o; dinv[base+0] = rsqrtf((float)(c0+1)); } o += c0;
  if (base+1 < N){ rowp[base+1] = o; rowp2[base+1] = o; dinv[base+1] = rsqrtf((float)(c1+1)); } o += c1;
  if (base+2 < N){ rowp[base+2] = o; rowp2[base+2] = o; dinv[base+2] = rsqrtf((float)(c2+1)); } o += c2;
  if (base+3 < N){ rowp[base+3] = o; rowp2[base+3] = o; dinv[base+3] = rsqrtf((float)(c3+1)); }
}

__global__ void k_scatter(const int* __restrict__ ei, int E, const int* __restrict__ flag,
                          int* __restrict__ rowp2,
                          const float* __restrict__ dinv, int2* __restrict__ epack){
  int e = blockIdx.x*blockDim.x + threadIdx.x;
  if (e >= E) return;
  int s, d;
  if (flag[0]){ s = ei[2*e]; d = ei[2*E + 2*e]; }
  else        { s = ei[e];   d = ei[E + e];     }
  int pos = atomicAdd(&rowp2[d], 1);
  int2 ev; ev.x = s; ev.y = __float_as_int(dinv[s] * dinv[d]);
  epack[pos] = ev;
}

// GEMM v7: B (128x128 bf16 = 32KB) in LDS, XOR-swizzled. MFMA operands swapped
// (mfma(b,a) => C^T frags); epilogue bounces through per-wave swizzled LDS tile
// for dwordx4 coalesced row stores. MODE 1 = f32 A (cast), with degree-count
// blocks appended to the grid (blockIdx >= ngemmb). MODE 2 = bf16 A with fused
// BatchNorm+ReLU. launch_bounds(256,3): 3 blocks/CU (147KB LDS), 12 waves/CU.
template<int MODE>
__global__ __launch_bounds__(256, 3) void k_gemm(const void* __restrict__ A,
                                const short* __restrict__ BT, short* __restrict__ C, int N,
                                const float* __restrict__ gpart, const float* __restrict__ gamma,
                                const float* __restrict__ beta,
                                const int* __restrict__ ei, int E, const int* __restrict__ flag,
                                int* __restrict__ deg, int ngemmb){
  if (MODE == 1 && (int)blockIdx.x >= ngemmb){
    int cb = blockIdx.x - ngemmb;
    int e0 = cb*1024 + threadIdx.x;
    int f = flag[0];
    #pragma unroll
    for (int r = 0; r < 4; ++r){
      int e = e0 + r*256;
      if (e < E){
        int d = f ? ei[2*E + 2*e] : ei[E + e];
        atomicAdd(&deg[d], 1);
      }
    }
    return;
  }
  __shared__ short ldsB[16384];     // [row=col-of-W 128][k 128], chunk-swizzled
  __shared__ short ldsC[4*2048];    // per-wave 16x128 epilogue tile
  __shared__ __align__(16) float s_sc[128];
  __shared__ __align__(16) float s_sh[128];
  int w = threadIdx.x >> 6;
  int lane = threadIdx.x & 63;
  int m = lane & 15, quad = lane >> 4;

  if (MODE == 2 && threadIdx.x < 128){
    int f = threadIdx.x;
    float s = 0.f, q = 0.f;
    #pragma unroll
    for (int i = 0; i < 8; ++i){ s += gpart[i*256 + f]; q += gpart[i*256 + 128 + f]; }
    float inv = 1.f / (float)N;
    float mean = s * inv;
    float var  = q * inv - mean*mean;   // biased, matches torch BN batch stats
    float sc = gamma[f] * rsqrtf(var + EPSV);
    s_sc[f] = sc;
    s_sh[f] = beta[f] - mean * sc;
  }
  // stage B into LDS with chunk XOR swizzle
  {
    const bf16x8* BTv = (const bf16x8*)BT;
    bf16x8* Bw = (bf16x8*)ldsB;
    for (int g = threadIdx.x; g < 2048; g += 256){
      int row = g >> 4, ch = g & 15;
      Bw[row*16 + (ch ^ (row & 15))] = BTv[g];
    }
  }
  __syncthreads();
  const bf16x8* Bv = (const bf16x8*)ldsB;
  short* cw = ldsC + w*2048;

  int tiles = (N + 31) >> 5;
  int wid = blockIdx.x*4 + w;
  int wstride = ngemmb*4;
  for (int tile = wid; tile < tiles; tile += wstride){
    int r0 = tile << 5;
    bf16x8 a[2][4];
    #pragma unroll
    for (int g = 0; g < 2; ++g){
      int row = r0 + g*16 + m;
      if (row >= N) row = N - 1;
      #pragma unroll
      for (int kc = 0; kc < 4; ++kc){
        int k0 = kc*32 + quad*8;
        if (MODE == 1){
          const float* Af = (const float*)A + (size_t)row*D + k0;
          float4 u = *(const float4*)Af;
          float4 v = *(const float4*)(Af + 4);
          bf16x8 tv;
          tv[0]=f2bf(u.x); tv[1]=f2bf(u.y); tv[2]=f2bf(u.z); tv[3]=f2bf(u.w);
          tv[4]=f2bf(v.x); tv[5]=f2bf(v.y); tv[6]=f2bf(v.z); tv[7]=f2bf(v.w);
          a[g][kc] = tv;
        } else {
          bf16x8 raw = *(const bf16x8*)((const short*)A + (size_t)row*D + k0);
          float4 s0v = *(const float4*)(s_sc + k0);
          float4 s1v = *(const float4*)(s_sc + k0 + 4);
          float4 h0v = *(const float4*)(s_sh + k0);
          float4 h1v = *(const float4*)(s_sh + k0 + 4);
          bf16x8 tv;
          tv[0] = f2bf(fmaxf(fmaf(bf2f(raw[0]), s0v.x, h0v.x), 0.f));
          tv[1] = f2bf(fmaxf(fmaf(bf2f(raw[1]), s0v.y, h0v.y), 0.f));
          tv[2] = f2bf(fmaxf(fmaf(bf2f(raw[2]), s0v.z, h0v.z), 0.f));
          tv[3] = f2bf(fmaxf(fmaf(bf2f(raw[3]), s0v.w, h0v.w), 0.f));
          tv[4] = f2bf(fmaxf(fmaf(bf2f(raw[4]), s1v.x, h1v.x), 0.f));
          tv[5] = f2bf(fmaxf(fmaf(bf2f(raw[5]), s1v.y, h1v.y), 0.f));
          tv[6] = f2bf(fmaxf(fmaf(bf2f(raw[6]), s1v.z, h1v.z), 0.f));
          tv[7] = f2bf(fmaxf(fmaf(bf2f(raw[7]), s1v.w, h1v.w), 0.f));
          a[g][kc] = tv;
        }
      }
    }
    f32x4 acc[2][8];
    #pragma unroll
    for (int g = 0; g < 2; ++g)
      #pragma unroll
      for (int c = 0; c < 8; ++c) acc[g][c] = (f32x4){0.f,0.f,0.f,0.f};
    #pragma unroll
    for (int kc = 0; kc < 4; ++kc){
      bf16x8 bb[8];
      #pragma unroll
      for (int c = 0; c < 8; ++c)
        bb[c] = Bv[(c*16 + m)*16 + ((kc*4 + quad) ^ m)];
      #pragma unroll
      for (int g = 0; g < 2; ++g)
        #pragma unroll
        for (int c = 0; c < 8; ++c)
          acc[g][c] = __builtin_amdgcn_mfma_f32_16x16x32_bf16(bb[c], a[g][kc], acc[g][c], 0, 0, 0);
    }
    // epilogue: per 16-row group, pack -> LDS (swizzled) -> coalesced dwordx4
    #pragma unroll
    for (int g = 0; g < 2; ++g){
      #pragma unroll
      for (int c = 0; c < 8; ++c){
        uint2 v;
        v.x = packbf(acc[g][c][0], acc[g][c][1]);
        v.y = packbf(acc[g][c][2], acc[g][c][3]);
        int x = c*2 + (quad >> 1);
        *(uint2*)&cw[m*128 + ((x ^ m) << 3) + ((quad & 1) << 2)] = v;
      }
      asm volatile("s_waitcnt lgkmcnt(0)" ::: "memory");
      #pragma unroll
      for (int rg = 0; rg < 4; ++rg){
        int lrow = rg*4 + quad;
        int rr = r0 + g*16 + lrow;
        uint4 v = *(const uint4*)&cw[lrow*128 + ((m ^ lrow) << 3)];
        if (rr < N) *(uint4*)(C + (size_t)rr*D + m*8) = v;
      }
      asm volatile("s_waitcnt lgkmcnt(0)" ::: "memory");
    }
  }
}

// Aggregation v3 (software-pipelined): grid-stride, one node per wave per step;
// lane p holds features 2p,2p+1. Prefetch next node's (rowp,deg,dinv,self-row,
// epack chunk) while current node's gathers are in flight. Gathers issue in
// batches of 8 independent loads via shfl broadcast. OUTF32==0 adds BN stats.
template<int OUTF32>
__global__ __launch_bounds__(256) void k_agg(const short* __restrict__ H, const int* __restrict__ rowp,
        const int* __restrict__ deg, const int2* __restrict__ epack, const float* __restrict__ dinv,
        const float* __restrict__ bias, void* __restrict__ out, int N, float* __restrict__ gpart){
  int w = threadIdx.x >> 6, p = threadIdx.x & 63;
  int wid = blockIdx.x*4 + w, wstride = gridDim.x*4;
  const unsigned* Hu = (const unsigned*)H;
  float S0=0.f, S1=0.f, Q0=0.f, Q1=0.f;
  float bb0=0.f, bb1=0.f;
  if (OUTF32){ bb0 = bias[2*p]; bb1 = bias[2*p+1]; }

  int n = wid;
  int start=0, cnt=0; float d1=0.f; unsigned u=0; int2 ev; ev.x=0; ev.y=0;
  if (n < N){
    start = rowp[n]; cnt = deg[n]; d1 = dinv[n];
    u = Hu[(size_t)n*64 + p];
    int nb = cnt < 64 ? cnt : 64;
    if (p < nb) ev = epack[start + p];
  }
  while (n < N){
    int n2 = n + wstride;
    int start2=0, cnt2=0; float d12=0.f; unsigned u2=0; int2 ev2; ev2.x=0; ev2.y=0;
    if (n2 < N){
      start2 = rowp[n2]; cnt2 = deg[n2]; d12 = dinv[n2];
      u2 = Hu[(size_t)n2*64 + p];
      int nb2 = cnt2 < 64 ? cnt2 : 64;
      if (p < nb2) ev2 = epack[start2 + p];
    }
    float w0 = d1*d1;
    float a0 = w0 * bflo(u), a1 = w0 * bfhi(u);
    int nb = cnt < 64 ? cnt : 64;
    for (int j = 0; j < nb; j += 8){
      int s0 = __shfl(ev.x, j+0), s1 = __shfl(ev.x, j+1);
      int s2 = __shfl(ev.x, j+2), s3 = __shfl(ev.x, j+3);
      int s4 = __shfl(ev.x, j+4), s5 = __shfl(ev.x, j+5);
      int s6 = __shfl(ev.x, j+6), s7 = __shfl(ev.x, j+7);
      float f0 = __int_as_float(__shfl(ev.y, j+0));
      float f1 = __int_as_float(__shfl(ev.y, j+1));
      float f2 = __int_as_float(__shfl(ev.y, j+2));
      float f3 = __int_as_float(__shfl(ev.y, j+3));
      float f4 = __int_as_float(__shfl(ev.y, j+4));
      float f5 = __int_as_float(__shfl(ev.y, j+5));
      float f6 = __int_as_float(__shfl(ev.y, j+6));
      float f7 = __int_as_float(__shfl(ev.y, j+7));
      unsigned u0 = Hu[(size_t)s0*64 + p], u1 = Hu[(size_t)s1*64 + p];
      unsigned u2g = Hu[(size_t)s2*64 + p], u3 = Hu[(size_t)s3*64 + p];
      unsigned u4 = Hu[(size_t)s4*64 + p], u5 = Hu[(size_t)s5*64 + p];
      unsigned u6 = Hu[(size_t)s6*64 + p], u7 = Hu[(size_t)s7*64 + p];
      a0 = fmaf(f0, bflo(u0), a0); a1 = fmaf(f0, bfhi(u0), a1);
      a0 = fmaf(f1, bflo(u1), a0); a1 = fmaf(f1, bfhi(u1), a1);
      a0 = fmaf(f2, bflo(u2g), a0); a1 = fmaf(f2, bfhi(u2g), a1);
      a0 = fmaf(f3, bflo(u3), a0); a1 = fmaf(f3, bfhi(u3), a1);
      a0 = fmaf(f4, bflo(u4), a0); a1 = fmaf(f4, bfhi(u4), a1);
      a0 = fmaf(f5, bflo(u5), a0); a1 = fmaf(f5, bfhi(u5), a1);
      a0 = fmaf(f6, bflo(u6), a0); a1 = fmaf(f6, bfhi(u6), a1);
      a0 = fmaf(f7, bflo(u7), a0); a1 = fmaf(f7, bfhi(u7), a1);
    }
    // rare overflow chunks (deg > 64)
    for (int base = 64; base < cnt; base += 64){
      int nbx = cnt - base; if (nbx > 64) nbx = 64;
      int2 evx; evx.x = 0; evx.y = 0;
      if (p < nbx) evx = epack[start + base + p];
      for (int j = 0; j < nbx; j += 8){
        #pragma unroll
        for (int q2 = 0; q2 < 8; ++q2){
          int sx = __shfl(evx.x, j+q2);
          float fx = __int_as_float(__shfl(evx.y, j+q2));
          unsigned ux = Hu[(size_t)sx*64 + p];
          a0 = fmaf(fx, bflo(ux), a0); a1 = fmaf(fx, bfhi(ux), a1);
        }
      }
    }
    if (OUTF32){
      float2 r; r.x = a0 + bb0; r.y = a1 + bb1;
      ((float2*)out)[(size_t)n*64 + p] = r;
    } else {
      ((unsigned*)out)[(size_t)n*64 + p] = packbf(a0, a1);
      S0 += a0; Q0 += a0*a0; S1 += a1; Q1 += a1*a1;
    }
    n = n2; start = start2; cnt = cnt2; d1 = d12; u = u2; ev = ev2;
  }
  if (!OUTF32){
    __shared__ float ls[1024];
    int base = w*256;
    ls[base + 2*p]       = S0;
    ls[base + 2*p + 1]   = S1;
    ls[base + 128 + 2*p]     = Q0;
    ls[base + 128 + 2*p + 1] = Q1;
    __syncthreads();
    int t = threadIdx.x;   // t<128: sum[f=t]; t>=128: sq[f=t-128]
    float v = ls[t] + ls[256 + t] + ls[512 + t] + ls[768 + t];
    atomicAdd(&gpart[(blockIdx.x & 7)*256 + t], v);
  }
}

extern "C" void kernel_launch(void* const* d_in, const int* in_sizes, int n_in,
                              void* d_out, int out_size, void* d_ws, size_t ws_size,
                              hipStream_t stream){
  const float* x   = (const float*)d_in[0];
  const int*   ei  = (const int*)  d_in[1];
  const float* W1  = (const float*)d_in[2];
  // d_in[3] = b1: cancels in BatchNorm, unused
  const float* g1  = (const float*)d_in[4];
  const float* be1 = (const float*)d_in[5];
  const float* W2  = (const float*)d_in[6];
  const float* b2  = (const float*)d_in[7];
  float* out = (float*)d_out;
  int N = in_sizes[0] / D;
  int E = in_sizes[1] / 2;

  char* w = (char*)d_ws;
  auto carve = [&](size_t bytes)->char*{ char* p = w; w += (bytes + 255) & ~(size_t)255; return p; };
  int*   flag  = (int*)  carve(256);
  int*   degA  = (int*)  carve((size_t)N*4);
  float* dinvA = (float*)carve((size_t)N*4);
  int*   rowp  = (int*)  carve((size_t)N*4);
  int*   rowp2 = (int*)  carve((size_t)N*4);
  int*   sagg  = (int*)  carve(512);
  int*   sinc  = (int*)  carve(512);
  int*   sflg  = (int*)  carve(512);
  int2*  epack = (int2*) carve((size_t)E*8);
  float* gpart = (float*)carve(2048*4);
  short* w1t   = (short*)carve((size_t)D*D*2);
  short* w2t   = (short*)carve((size_t)D*D*2);
  short* h1    = (short*)carve((size_t)N*D*2);   // GEMM1 out; reused as GEMM2 out
  short* hb    = (short*)carve((size_t)N*D*2);   // agg1 out (pre-BN h)

  const int TB = 256;
  int EB  = (E + TB - 1) / TB;
  int NBt = (N + TB - 1) / TB;
  int NB1024 = (N + 1023) / 1024;
  int GEMMB = 768;                 // gemm blocks: 3/CU by LDS (147KB), 12 waves/CU
  int CNTB  = (E + 1023) / 1024;   // count blocks appended to gemm1 grid
  int AGGB  = 2048;                // 8 blocks/CU = 32 waves/CU

  k_init    <<<NBt, TB, 0, stream>>>(N, E, ei, flag, degA, gpart, sflg, W1, W2, w1t, w2t);
  k_gemm<1> <<<GEMMB + CNTB, 256, 0, stream>>>(x, w1t, h1, N, nullptr, nullptr, nullptr,
                                               ei, E, flag, degA, GEMMB);
  k_scan    <<<NB1024, 256, 0, stream>>>(degA, N, rowp, rowp2, dinvA, sagg, sinc, sflg);
  k_scatter <<<EB, TB, 0, stream>>>(ei, E, flag, rowp2, dinvA, epack);
  k_agg<0>  <<<AGGB, 256, 0, stream>>>(h1, rowp, degA, epack, dinvA, nullptr, hb, N, gpart);
  k_gemm<2> <<<GEMMB, 256, 0, stream>>>(hb, w2t, h1, N, gpart, g1, be1,
                                        nullptr, 0, nullptr, nullptr, GEMMB);
  k_agg<1>  <<<AGGB, 256, 0, stream>>>(h1, rowp, degA, epack, dinvA, b2, out, N, nullptr);
}

// Round 3
// 243.678 us; speedup vs baseline: 1.8457x; 1.1335x over previous
//
#include <hip/hip_runtime.h>

#define D 128
#define EPSV 1e-5f

typedef __attribute__((ext_vector_type(8))) short bf16x8;
typedef __attribute__((ext_vector_type(4))) float f32x4;

__device__ __forceinline__ short f2bf(float f){
  unsigned u = __float_as_uint(f);
  u += 0x7fffu + ((u >> 16) & 1u);          // RNE
  return (short)(u >> 16);
}
__device__ __forceinline__ float bflo(unsigned u){ return __uint_as_float(u << 16); }
__device__ __forceinline__ float bfhi(unsigned u){ return __uint_as_float(u & 0xffff0000u); }
__device__ __forceinline__ float bf2f(short s){ return __uint_as_float(((unsigned)(unsigned short)s) << 16); }
__device__ __forceinline__ unsigned packbf(float a, float b){
  unsigned lo = (unsigned short)f2bf(a);
  unsigned hi = (unsigned short)f2bf(b);
  return lo | (hi << 16);
}

// Fused init: detect int64-vs-int32 edge layout (block 0), zero deg/gpart/
// scan-flags, transpose W1,W2 -> bf16 [out_col][k] (16B-contiguous B frags).
__global__ void k_init(int N, int E, const int* __restrict__ ei, int* __restrict__ flag,
                       int* __restrict__ deg, float* __restrict__ gpart,
                       int* __restrict__ sflg,
                       const float* __restrict__ W1, const float* __restrict__ W2,
                       short* __restrict__ w1t, short* __restrict__ w2t){
  int i = blockIdx.x*blockDim.x + threadIdx.x;
  if (i < N) deg[i] = 0;
  if (i < D*D){
    int j = i >> 7, k = i & 127;
    w1t[i] = f2bf(W1[k*D + j]);
    w2t[i] = f2bf(W2[k*D + j]);
  }
  if (i < 2048) gpart[i] = 0.f;
  if (i < 128) sflg[i] = 0;
  if (blockIdx.x == 0){
    __shared__ int any;
    int t = threadIdx.x;
    if (t == 0) any = 0;
    __syncthreads();
    if (2*t+1 < 2*E && ei[2*t+1] != 0) atomicOr(&any, 1);
    __syncthreads();
    if (t == 0) flag[0] = (any == 0) ? 1 : 0;   // 1 => int64 layout
  }
}

// One-kernel scan: per-1024-node block sums + decoupled lookback (device-scope
// atomics; all 98 blocks co-resident => deadlock-free). Writes rowp AND dinv.
__global__ void k_scan(const int* __restrict__ deg, int N, int* __restrict__ rowp,
                       float* __restrict__ dinv, int* __restrict__ s_agg,
                       int* __restrict__ s_inc, int* __restrict__ s_flg){
  __shared__ int sh[256];
  __shared__ int s_ex;
  int b = blockIdx.x, t = threadIdx.x;
  int base = b*1024 + t*4;
  int c0 = (base+0 < N) ? deg[base+0] : 0;
  int c1 = (base+1 < N) ? deg[base+1] : 0;
  int c2 = (base+2 < N) ? deg[base+2] : 0;
  int c3 = (base+3 < N) ? deg[base+3] : 0;
  int s = c0 + c1 + c2 + c3;
  sh[t] = s; __syncthreads();
  for (int d = 1; d < 256; d <<= 1){
    int v = (t >= d) ? sh[t-d] : 0;
    __syncthreads();
    sh[t] += v;
    __syncthreads();
  }
  int total = sh[255];
  if (t == 0){
    atomicExch(&s_agg[b], total);
    __threadfence();
    atomicExch(&s_flg[b], 1);
    int ex = 0;
    for (int i = b-1; i >= 0; ){
      int f;
      while ((f = atomicAdd(&s_flg[i], 0)) == 0) __builtin_amdgcn_s_sleep(1);
      if (f == 2){ ex += atomicAdd(&s_inc[i], 0); break; }
      ex += atomicAdd(&s_agg[i], 0); --i;
    }
    atomicExch(&s_inc[b], ex + total);
    __threadfence();
    atomicExch(&s_flg[b], 2);
    s_ex = ex;
  }
  __syncthreads();
  int o = sh[t] - s + s_ex;
  if (base+0 < N){ rowp[base+0] = o; dinv[base+0] = rsqrtf((float)(c0+1)); } o += c0;
  if (base+1 < N){ rowp[base+1] = o; dinv[base+1] = rsqrtf((float)(c1+1)); } o += c1;
  if (base+2 < N){ rowp[base+2] = o; dinv[base+2] = rsqrtf((float)(c2+1)); } o += c2;
  if (base+3 < N){ rowp[base+3] = o; dinv[base+3] = rsqrtf((float)(c3+1)); }
}

// Scatter v2: NO atomics. The count phase saved each edge's within-node slot
// (the atomicAdd return value); pos = rowp[d] + slot[e] is a pure load chain.
__global__ void k_scatter(const int* __restrict__ ei, int E, const int* __restrict__ flag,
                          const int* __restrict__ rowp, const int* __restrict__ slot,
                          const float* __restrict__ dinv, int2* __restrict__ epack){
  int e = blockIdx.x*blockDim.x + threadIdx.x;
  if (e >= E) return;
  int s, d;
  if (flag[0]){ s = ei[2*e]; d = ei[2*E + 2*e]; }
  else        { s = ei[e];   d = ei[E + e];     }
  int pos = rowp[d] + slot[e];
  int2 ev; ev.x = s; ev.y = __float_as_int(dinv[s] * dinv[d]);
  epack[pos] = ev;
}

// GEMM v8: B (128x128 bf16 = 32KB) in LDS, XOR-swizzled. MFMA operands swapped
// (mfma(b,a) => C^T frags); epilogue bounces through per-wave swizzled LDS tile
// for dwordx4 coalesced row stores. MODE 1 = f32 A (cast), with degree-count
// blocks appended to the grid (blockIdx >= ngemmb) — GEMMB=512 occupies only
// 2 of the 3 LDS-limited block slots per CU, so count blocks run CONCURRENTLY
// in the 3rd slot (this overlap is worth ~15 µs; do not fill all slots with
// gemm blocks). Count phase also records slot[e] = within-dst arrival index.
// MODE 2 = bf16 A with fused BatchNorm+ReLU.
template<int MODE>
__global__ __launch_bounds__(256, 2) void k_gemm(const void* __restrict__ A,
                                const short* __restrict__ BT, short* __restrict__ C, int N,
                                const float* __restrict__ gpart, const float* __restrict__ gamma,
                                const float* __restrict__ beta,
                                const int* __restrict__ ei, int E, const int* __restrict__ flag,
                                int* __restrict__ deg, int* __restrict__ slot, int ngemmb){
  if (MODE == 1 && (int)blockIdx.x >= ngemmb){
    int cb = blockIdx.x - ngemmb;
    int e0 = cb*1024 + threadIdx.x;
    int f = flag[0];
    #pragma unroll
    for (int r = 0; r < 4; ++r){
      int e = e0 + r*256;
      if (e < E){
        int d = f ? ei[2*E + 2*e] : ei[E + e];
        slot[e] = atomicAdd(&deg[d], 1);
      }
    }
    return;
  }
  __shared__ short ldsB[16384];     // [row=col-of-W 128][k 128], chunk-swizzled
  __shared__ short ldsC[4*2048];    // per-wave 16x128 epilogue tile
  __shared__ __align__(16) float s_sc[128];
  __shared__ __align__(16) float s_sh[128];
  int w = threadIdx.x >> 6;
  int lane = threadIdx.x & 63;
  int m = lane & 15, quad = lane >> 4;

  if (MODE == 2 && threadIdx.x < 128){
    int f = threadIdx.x;
    float s = 0.f, q = 0.f;
    #pragma unroll
    for (int i = 0; i < 8; ++i){ s += gpart[i*256 + f]; q += gpart[i*256 + 128 + f]; }
    float inv = 1.f / (float)N;
    float mean = s * inv;
    float var  = q * inv - mean*mean;   // biased, matches torch BN batch stats
    float sc = gamma[f] * rsqrtf(var + EPSV);
    s_sc[f] = sc;
    s_sh[f] = beta[f] - mean * sc;
  }
  // stage B into LDS with chunk XOR swizzle
  {
    const bf16x8* BTv = (const bf16x8*)BT;
    bf16x8* Bw = (bf16x8*)ldsB;
    for (int g = threadIdx.x; g < 2048; g += 256){
      int row = g >> 4, ch = g & 15;
      Bw[row*16 + (ch ^ (row & 15))] = BTv[g];
    }
  }
  __syncthreads();
  const bf16x8* Bv = (const bf16x8*)ldsB;
  short* cw = ldsC + w*2048;

  int tiles = (N + 31) >> 5;
  int wid = blockIdx.x*4 + w;
  int wstride = ngemmb*4;
  for (int tile = wid; tile < tiles; tile += wstride){
    int r0 = tile << 5;
    bf16x8 a[2][4];
    #pragma unroll
    for (int g = 0; g < 2; ++g){
      int row = r0 + g*16 + m;
      if (row >= N) row = N - 1;
      #pragma unroll
      for (int kc = 0; kc < 4; ++kc){
        int k0 = kc*32 + quad*8;
        if (MODE == 1){
          const float* Af = (const float*)A + (size_t)row*D + k0;
          float4 u = *(const float4*)Af;
          float4 v = *(const float4*)(Af + 4);
          bf16x8 tv;
          tv[0]=f2bf(u.x); tv[1]=f2bf(u.y); tv[2]=f2bf(u.z); tv[3]=f2bf(u.w);
          tv[4]=f2bf(v.x); tv[5]=f2bf(v.y); tv[6]=f2bf(v.z); tv[7]=f2bf(v.w);
          a[g][kc] = tv;
        } else {
          bf16x8 raw = *(const bf16x8*)((const short*)A + (size_t)row*D + k0);
          float4 s0v = *(const float4*)(s_sc + k0);
          float4 s1v = *(const float4*)(s_sc + k0 + 4);
          float4 h0v = *(const float4*)(s_sh + k0);
          float4 h1v = *(const float4*)(s_sh + k0 + 4);
          bf16x8 tv;
          tv[0] = f2bf(fmaxf(fmaf(bf2f(raw[0]), s0v.x, h0v.x), 0.f));
          tv[1] = f2bf(fmaxf(fmaf(bf2f(raw[1]), s0v.y, h0v.y), 0.f));
          tv[2] = f2bf(fmaxf(fmaf(bf2f(raw[2]), s0v.z, h0v.z), 0.f));
          tv[3] = f2bf(fmaxf(fmaf(bf2f(raw[3]), s0v.w, h0v.w), 0.f));
          tv[4] = f2bf(fmaxf(fmaf(bf2f(raw[4]), s1v.x, h1v.x), 0.f));
          tv[5] = f2bf(fmaxf(fmaf(bf2f(raw[5]), s1v.y, h1v.y), 0.f));
          tv[6] = f2bf(fmaxf(fmaf(bf2f(raw[6]), s1v.z, h1v.z), 0.f));
          tv[7] = f2bf(fmaxf(fmaf(bf2f(raw[7]), s1v.w, h1v.w), 0.f));
          a[g][kc] = tv;
        }
      }
    }
    f32x4 acc[2][8];
    #pragma unroll
    for (int g = 0; g < 2; ++g)
      #pragma unroll
      for (int c = 0; c < 8; ++c) acc[g][c] = (f32x4){0.f,0.f,0.f,0.f};
    #pragma unroll
    for (int kc = 0; kc < 4; ++kc){
      bf16x8 bb[8];
      #pragma unroll
      for (int c = 0; c < 8; ++c)
        bb[c] = Bv[(c*16 + m)*16 + ((kc*4 + quad) ^ m)];
      #pragma unroll
      for (int g = 0; g < 2; ++g)
        #pragma unroll
        for (int c = 0; c < 8; ++c)
          acc[g][c] = __builtin_amdgcn_mfma_f32_16x16x32_bf16(bb[c], a[g][kc], acc[g][c], 0, 0, 0);
    }
    // epilogue: per 16-row group, pack -> LDS (swizzled) -> coalesced dwordx4
    #pragma unroll
    for (int g = 0; g < 2; ++g){
      #pragma unroll
      for (int c = 0; c < 8; ++c){
        uint2 v;
        v.x = packbf(acc[g][c][0], acc[g][c][1]);
        v.y = packbf(acc[g][c][2], acc[g][c][3]);
        int x = c*2 + (quad >> 1);
        *(uint2*)&cw[m*128 + ((x ^ m) << 3) + ((quad & 1) << 2)] = v;
      }
      asm volatile("s_waitcnt lgkmcnt(0)" ::: "memory");
      #pragma unroll
      for (int rg = 0; rg < 4; ++rg){
        int lrow = rg*4 + quad;
        int rr = r0 + g*16 + lrow;
        uint4 v = *(const uint4*)&cw[lrow*128 + ((m ^ lrow) << 3)];
        if (rr < N) *(uint4*)(C + (size_t)rr*D + m*8) = v;
      }
      asm volatile("s_waitcnt lgkmcnt(0)" ::: "memory");
    }
  }
}

// Aggregation v3 (software-pipelined): grid-stride, one node per wave per step;
// lane p holds features 2p,2p+1. Prefetch next node's (rowp,deg,dinv,self-row,
// epack chunk) while current node's gathers are in flight. Gathers issue in
// batches of 8 independent loads via shfl broadcast. OUTF32==0 adds BN stats.
template<int OUTF32>
__global__ __launch_bounds__(256) void k_agg(const short* __restrict__ H, const int* __restrict__ rowp,
        const int* __restrict__ deg, const int2* __restrict__ epack, const float* __restrict__ dinv,
        const float* __restrict__ bias, void* __restrict__ out, int N, float* __restrict__ gpart){
  int w = threadIdx.x >> 6, p = threadIdx.x & 63;
  int wid = blockIdx.x*4 + w, wstride = gridDim.x*4;
  const unsigned* Hu = (const unsigned*)H;
  float S0=0.f, S1=0.f, Q0=0.f, Q1=0.f;
  float bb0=0.f, bb1=0.f;
  if (OUTF32){ bb0 = bias[2*p]; bb1 = bias[2*p+1]; }

  int n = wid;
  int start=0, cnt=0; float d1=0.f; unsigned u=0; int2 ev; ev.x=0; ev.y=0;
  if (n < N){
    start = rowp[n]; cnt = deg[n]; d1 = dinv[n];
    u = Hu[(size_t)n*64 + p];
    int nb = cnt < 64 ? cnt : 64;
    if (p < nb) ev = epack[start + p];
  }
  while (n < N){
    int n2 = n + wstride;
    int start2=0, cnt2=0; float d12=0.f; unsigned u2=0; int2 ev2; ev2.x=0; ev2.y=0;
    if (n2 < N){
      start2 = rowp[n2]; cnt2 = deg[n2]; d12 = dinv[n2];
      u2 = Hu[(size_t)n2*64 + p];
      int nb2 = cnt2 < 64 ? cnt2 : 64;
      if (p < nb2) ev2 = epack[start2 + p];
    }
    float w0 = d1*d1;
    float a0 = w0 * bflo(u), a1 = w0 * bfhi(u);
    int nb = cnt < 64 ? cnt : 64;
    for (int j = 0; j < nb; j += 8){
      int s0 = __shfl(ev.x, j+0), s1 = __shfl(ev.x, j+1);
      int s2 = __shfl(ev.x, j+2), s3 = __shfl(ev.x, j+3);
      int s4 = __shfl(ev.x, j+4), s5 = __shfl(ev.x, j+5);
      int s6 = __shfl(ev.x, j+6), s7 = __shfl(ev.x, j+7);
      float f0 = __int_as_float(__shfl(ev.y, j+0));
      float f1 = __int_as_float(__shfl(ev.y, j+1));
      float f2 = __int_as_float(__shfl(ev.y, j+2));
      float f3 = __int_as_float(__shfl(ev.y, j+3));
      float f4 = __int_as_float(__shfl(ev.y, j+4));
      float f5 = __int_as_float(__shfl(ev.y, j+5));
      float f6 = __int_as_float(__shfl(ev.y, j+6));
      float f7 = __int_as_float(__shfl(ev.y, j+7));
      unsigned u0 = Hu[(size_t)s0*64 + p], u1 = Hu[(size_t)s1*64 + p];
      unsigned u2g = Hu[(size_t)s2*64 + p], u3 = Hu[(size_t)s3*64 + p];
      unsigned u4 = Hu[(size_t)s4*64 + p], u5 = Hu[(size_t)s5*64 + p];
      unsigned u6 = Hu[(size_t)s6*64 + p], u7 = Hu[(size_t)s7*64 + p];
      a0 = fmaf(f0, bflo(u0), a0); a1 = fmaf(f0, bfhi(u0), a1);
      a0 = fmaf(f1, bflo(u1), a0); a1 = fmaf(f1, bfhi(u1), a1);
      a0 = fmaf(f2, bflo(u2g), a0); a1 = fmaf(f2, bfhi(u2g), a1);
      a0 = fmaf(f3, bflo(u3), a0); a1 = fmaf(f3, bfhi(u3), a1);
      a0 = fmaf(f4, bflo(u4), a0); a1 = fmaf(f4, bfhi(u4), a1);
      a0 = fmaf(f5, bflo(u5), a0); a1 = fmaf(f5, bfhi(u5), a1);
      a0 = fmaf(f6, bflo(u6), a0); a1 = fmaf(f6, bfhi(u6), a1);
      a0 = fmaf(f7, bflo(u7), a0); a1 = fmaf(f7, bfhi(u7), a1);
    }
    // rare overflow chunks (deg > 64)
    for (int base = 64; base < cnt; base += 64){
      int nbx = cnt - base; if (nbx > 64) nbx = 64;
      int2 evx; evx.x = 0; evx.y = 0;
      if (p < nbx) evx = epack[start + base + p];
      for (int j = 0; j < nbx; j += 8){
        #pragma unroll
        for (int q2 = 0; q2 < 8; ++q2){
          int sx = __shfl(evx.x, j+q2);
          float fx = __int_as_float(__shfl(evx.y, j+q2));
          unsigned ux = Hu[(size_t)sx*64 + p];
          a0 = fmaf(fx, bflo(ux), a0); a1 = fmaf(fx, bfhi(ux), a1);
        }
      }
    }
    if (OUTF32){
      float2 r; r.x = a0 + bb0; r.y = a1 + bb1;
      ((float2*)out)[(size_t)n*64 + p] = r;
    } else {
      ((unsigned*)out)[(size_t)n*64 + p] = packbf(a0, a1);
      S0 += a0; Q0 += a0*a0; S1 += a1; Q1 += a1*a1;
    }
    n = n2; start = start2; cnt = cnt2; d1 = d12; u = u2; ev = ev2;
  }
  if (!OUTF32){
    __shared__ float ls[1024];
    int base = w*256;
    ls[base + 2*p]       = S0;
    ls[base + 2*p + 1]   = S1;
    ls[base + 128 + 2*p]     = Q0;
    ls[base + 128 + 2*p + 1] = Q1;
    __syncthreads();
    int t = threadIdx.x;   // t<128: sum[f=t]; t>=128: sq[f=t-128]
    float v = ls[t] + ls[256 + t] + ls[512 + t] + ls[768 + t];
    atomicAdd(&gpart[(blockIdx.x & 7)*256 + t], v);
  }
}

extern "C" void kernel_launch(void* const* d_in, const int* in_sizes, int n_in,
                              void* d_out, int out_size, void* d_ws, size_t ws_size,
                              hipStream_t stream){
  const float* x   = (const float*)d_in[0];
  const int*   ei  = (const int*)  d_in[1];
  const float* W1  = (const float*)d_in[2];
  // d_in[3] = b1: cancels in BatchNorm, unused
  const float* g1  = (const float*)d_in[4];
  const float* be1 = (const float*)d_in[5];
  const float* W2  = (const float*)d_in[6];
  const float* b2  = (const float*)d_in[7];
  float* out = (float*)d_out;
  int N = in_sizes[0] / D;
  int E = in_sizes[1] / 2;

  char* w = (char*)d_ws;
  auto carve = [&](size_t bytes)->char*{ char* p = w; w += (bytes + 255) & ~(size_t)255; return p; };
  int*   flag  = (int*)  carve(256);
  int*   degA  = (int*)  carve((size_t)N*4);
  float* dinvA = (float*)carve((size_t)N*4);
  int*   rowp  = (int*)  carve((size_t)N*4);
  int*   slot  = (int*)  carve((size_t)E*4);
  int*   sagg  = (int*)  carve(512);
  int*   sinc  = (int*)  carve(512);
  int*   sflg  = (int*)  carve(512);
  int2*  epack = (int2*) carve((size_t)E*8);
  float* gpart = (float*)carve(2048*4);
  short* w1t   = (short*)carve((size_t)D*D*2);
  short* w2t   = (short*)carve((size_t)D*D*2);
  short* h1    = (short*)carve((size_t)N*D*2);   // GEMM1 out; reused as GEMM2 out
  short* hb    = (short*)carve((size_t)N*D*2);   // agg1 out (pre-BN h)

  const int TB = 256;
  int EB  = (E + TB - 1) / TB;
  int NBt = (N + TB - 1) / TB;
  int NB1024 = (N + 1023) / 1024;
  int GEMMB = 512;                 // 2/CU of gemm; 3rd LDS slot left for count blocks
  int CNTB  = (E + 1023) / 1024;   // count blocks appended to gemm1 grid (overlap!)
  int AGGB  = 2048;                // 8 blocks/CU = 32 waves/CU

  k_init    <<<NBt, TB, 0, stream>>>(N, E, ei, flag, degA, gpart, sflg, W1, W2, w1t, w2t);
  k_gemm<1> <<<GEMMB + CNTB, 256, 0, stream>>>(x, w1t, h1, N, nullptr, nullptr, nullptr,
                                               ei, E, flag, degA, slot, GEMMB);
  k_scan    <<<NB1024, 256, 0, stream>>>(degA, N, rowp, dinvA, sagg, sinc, sflg);
  k_scatter <<<EB, TB, 0, stream>>>(ei, E, flag, rowp, slot, dinvA, epack);
  k_agg<0>  <<<AGGB, 256, 0, stream>>>(h1, rowp, degA, epack, dinvA, nullptr, hb, N, gpart);
  k_gemm<2> <<<GEMMB, 256, 0, stream>>>(hb, w2t, h1, N, gpart, g1, be1,
                                        nullptr, 0, nullptr, nullptr, nullptr, GEMMB);
  k_agg<1>  <<<AGGB, 256, 0, stream>>>(h1, rowp, degA, epack, dinvA, b2, out, N, nullptr);
}